// Round 11
// baseline (116.913 us; speedup 1.0000x reference)
//
#include <hip/hip_runtime.h>
#include <math.h>

// Problem constants (b=2, c=32, H=W=256, 256 superpixels, R=1, 5 iters, tau=0.01)
#define TAU_INV 100.0f
// Fixed softmax shift: dots of unit vectors lie in [-1,1]; every cell window's
// max dot is > 0, so with shift 0.5 exponents are in [-150, 50]: e <= 5.2e21
// (no overflow), den > 0 (no all-zero window). Softmax is shift-invariant, so
// ratios match the reference's true-max softmax. Downstream divides by den
// BEFORE squaring (convex combination, ||mean|| <= 1) to avoid f32 overflow.
#define SHIFTED_EXP(s) expf(((s) - 0.5f) * TAU_INV)

// dot of fv[32] (regs) with a 16B-aligned LDS row, via ds_read_b128.
// Same FMA order as the scalar loop -> bit-identical results.
__device__ inline float dot32_lds(const float* __restrict__ fv,
                                  const float* __restrict__ row) {
    const float4* r4 = (const float4*)row;
    float s = 0.f;
#pragma unroll
    for (int j = 0; j < 8; ++j) {
        float4 cv = r4[j];
        s = fmaf(fv[4*j + 0], cv.x, s);
        s = fmaf(fv[4*j + 1], cv.y, s);
        s = fmaf(fv[4*j + 2], cv.z, s);
        s = fmaf(fv[4*j + 3], cv.w, s);
    }
    return s;
}

// ---------------------------------------------------------------------------
// combine_one: cluster update for target cell (ti,tj) from iteration partials.
// Executed by an aligned 32-lane group; c = lane's channel. Deterministic
// (fixed summation order) so redundant recomputation in different blocks is
// bitwise identical. Returns 0 for out-of-grid targets (matches zero-padding).
// ---------------------------------------------------------------------------
__device__ inline float combine_one(const float* __restrict__ Sin,
                                    const float* __restrict__ dpin,
                                    int b, int ti, int tj, int c) {
    float acc = 0.f, den = 0.f;
    if (ti >= 0 && ti < 16 && tj >= 0 && tj < 16) {
#pragma unroll
        for (int u = 0; u < 9; ++u) {
            int oy = u / 3 - 1, ox = u % 3 - 1;
            int ii = ti + oy, jj = tj + ox;
            if (ii >= 0 && ii < 16 && jj >= 0 && jj < 16) {
                int src = ((b * 256 + ii * 16 + jj) * 9) + (1 - oy) * 3 + (1 - ox);
                acc += Sin[(size_t)src * 32 + c];
                den += dpin[src];
            }
        }
    }
    float mean = (den > 0.f) ? acc / den : 0.f;   // ||mean|| <= 1
    float p = mean * mean;
#pragma unroll
    for (int k = 16; k >= 1; k >>= 1) p += __shfl_xor(p, k);
    return (p > 0.f) ? mean * (1.0f / sqrtf(p)) : 0.f;
}

// ---------------------------------------------------------------------------
// prep_init (512 thr): thread = (pixel p = t&255, channel-half h = t>>8).
//  - per-pixel L2-normalize x -> xn[b][y][x][c] (channel-last)
//  - raw block mean over the 16x16 block, L2-normalized -> clst0[b][cell][c]
// ---------------------------------------------------------------------------
__global__ __launch_bounds__(512, 4) void prep_init_kernel(const float* __restrict__ x,
                                                           float* __restrict__ xn,
                                                           float* __restrict__ clst0) {
    int blk = blockIdx.x;          // b*256 + cell
    int b = blk >> 8;
    int cell = blk & 255;
    int ci = cell >> 4, cj = cell & 15;
    int t = threadIdx.x;
    int p = t & 255, h = t >> 8;
    int py = p >> 4, px = p & 15;
    int rem = (ci * 16 + py) * 256 + cj * 16 + px;

    __shared__ float sraw[256 * 33];   // padded stride 33
    __shared__ float ssh[512];
    __shared__ float red[512];

    const float* xb = x + (size_t)b * (32 * 65536);
    float v[16];
    float ssp = 0.f;
#pragma unroll
    for (int k = 0; k < 16; ++k) {
        int c = h * 16 + k;
        float tv = xb[c * 65536 + rem];
        v[k] = tv;
        ssp += tv * tv;
        sraw[p * 33 + c] = tv;
    }
    ssh[t] = ssp;
    __syncthreads();
    float rn = 1.0f / sqrtf(ssh[p] + ssh[p + 256]);
    {
        float4* outp = (float4*)(xn + ((size_t)b * 65536 + rem) * 32 + h * 16);
#pragma unroll
        for (int q = 0; q < 4; ++q)
            outp[q] = make_float4(v[4*q]*rn, v[4*q+1]*rn, v[4*q+2]*rn, v[4*q+3]*rn);
    }
    // block mean: thread = (c = t&31, pg = t>>5, 16 groups of 16 pixels)
    {
        int c = t & 31, pg = t >> 5;
        float acc = 0.f;
#pragma unroll
        for (int k = 0; k < 16; ++k) acc += sraw[(pg * 16 + k) * 33 + c];
        red[t] = acc;
    }
    __syncthreads();
    if (t < 256) red[t] += red[t + 256];
    __syncthreads();
    if (t < 128) red[t] += red[t + 128];
    __syncthreads();
    if (t < 64) red[t] += red[t + 64];
    __syncthreads();
    if (t < 32) {
        float m = (red[t] + red[t + 32]) * (1.0f / 256.0f);
        float pp = m * m;
#pragma unroll
        for (int k = 16; k >= 1; k >>= 1) pp += __shfl_xor(pp, k);
        clst0[(size_t)blk * 32 + t] = m * (1.0f / sqrtf(pp));
    }
}

// ---------------------------------------------------------------------------
// accum9c (512 thr): one block per (b, pixel-block).
// Head: 9 neighbor clusters (clst0 at it==0, redundant combine at it>=1).
// Dots: thread = (pixel p = t&255, half h = t>>8); h=0 -> q 0..3, h=1 -> 4..8.
// All hot LDS reads are ds_read_b128 (sclst rows, se quads).
// Accumulation: thread = (c = t&31, pg = t>>5, 16 pixels each).
// ---------------------------------------------------------------------------
__global__ __launch_bounds__(512, 4) void accum9c_kernel(const float* __restrict__ xn,
                                                         const float* __restrict__ clst0,
                                                         const float* __restrict__ Sin,
                                                         const float* __restrict__ dpin,
                                                         float* __restrict__ Sout,
                                                         float* __restrict__ dpout,
                                                         float* __restrict__ clstin5,
                                                         int it) {
    int blk = blockIdx.x;           // b*256 + block
    int b = blk >> 8;
    int cell = blk & 255;
    int bi = cell >> 4, bj = cell & 15;
    int t = threadIdx.x;

    __shared__ float sx[256 * 33];              // block's pixel features
    __shared__ __align__(16) float se[9 * 256]; // e per (q, pixel)
    __shared__ float sacc[16 * 9 * 32];
    __shared__ __align__(16) float sclst[9][32];
    __shared__ float sdw[8][9];

    if (it == 0) {
        if (t < 288) {
            int q = t >> 5, c = t & 31;
            int ii = bi + q / 3 - 1, jj = bj + q % 3 - 1;
            float v = 0.f;
            if (ii >= 0 && ii < 16 && jj >= 0 && jj < 16)
                v = clst0[((size_t)(b * 256 + ii * 16 + jj)) * 32 + c];
            sclst[q][c] = v;
        }
    } else {
        if (t < 288) {
            int q = t >> 5, c = t & 31;
            float v = combine_one(Sin, dpin, b, bi + q / 3 - 1, bj + q % 3 - 1, c);
            sclst[q][c] = v;
            if (it == 4 && q == 4)                   // own cell = iter-5 input clst
                clstin5[(size_t)blk * 32 + c] = v;
        }
    }
    __syncthreads();

    int p = t & 255, h = t >> 8;
    int y = bi * 16 + (p >> 4), xx = bj * 16 + (p & 15);
    const float4* f4 = (const float4*)(xn + ((size_t)(b * 65536 + y * 256 + xx)) * 32);
    float fv[32];
#pragma unroll
    for (int q = 0; q < 8; ++q) {
        float4 v = f4[q];
        fv[4*q] = v.x; fv[4*q+1] = v.y; fv[4*q+2] = v.z; fv[4*q+3] = v.w;
    }
    {   // stage pixel features: halves split the channel range
#pragma unroll
        for (int k = 0; k < 16; ++k) {
            int c = h * 16 + k;
            sx[p * 33 + c] = fv[c];
        }
    }

    int wid = t >> 6, lane = t & 63;
    if (h == 0) {
#pragma unroll
        for (int q = 0; q < 4; ++q) {
            float s = dot32_lds(fv, sclst[q]);
            // s==0 <=> OOB target (sclst=0) or exact-zero dot; ref masks both.
            float ev = (s == 0.f) ? 0.f : SHIFTED_EXP(s);
            se[q * 256 + p] = ev;
            float d = ev;
#pragma unroll
            for (int k = 32; k >= 1; k >>= 1) d += __shfl_xor(d, k);
            if (lane == 0) sdw[wid][q] = d;
        }
    } else {
#pragma unroll
        for (int q = 4; q < 9; ++q) {
            float s = dot32_lds(fv, sclst[q]);
            float ev = (s == 0.f) ? 0.f : SHIFTED_EXP(s);
            se[q * 256 + p] = ev;
            float d = ev;
#pragma unroll
            for (int k = 32; k >= 1; k >>= 1) d += __shfl_xor(d, k);
            if (lane == 0) sdw[wid][q] = d;
        }
    }
    __syncthreads();
    if (t < 9) {
        int w0 = (t < 4) ? 0 : 4;
        dpout[blk * 9 + t] = sdw[w0][t] + sdw[w0+1][t] + sdw[w0+2][t] + sdw[w0+3][t];
    }

    // accumulation: thread = (c = t&31, pg = t>>5), 16 pixels each, 9 targets.
    // se read as float4 quads (b128, broadcast within c-group); same FMA order
    // per accumulator as the scalar version -> bit-identical.
    {
        int c = t & 31, pg = t >> 5;
        float acc[9];
#pragma unroll
        for (int q = 0; q < 9; ++q) acc[q] = 0.f;
#pragma unroll
        for (int k4 = 0; k4 < 4; ++k4) {
            int p0 = pg * 16 + k4 * 4;
            float xv0 = sx[(p0 + 0) * 33 + c];
            float xv1 = sx[(p0 + 1) * 33 + c];
            float xv2 = sx[(p0 + 2) * 33 + c];
            float xv3 = sx[(p0 + 3) * 33 + c];
#pragma unroll
            for (int q = 0; q < 9; ++q) {
                float4 e4 = *(const float4*)&se[q * 256 + p0];
                acc[q] = fmaf(e4.x, xv0, acc[q]);
                acc[q] = fmaf(e4.y, xv1, acc[q]);
                acc[q] = fmaf(e4.z, xv2, acc[q]);
                acc[q] = fmaf(e4.w, xv3, acc[q]);
            }
        }
#pragma unroll
        for (int q = 0; q < 9; ++q) sacc[(pg * 9 + q) * 32 + c] = acc[q];
    }
    __syncthreads();
    if (t < 288) {
        int q = t >> 5, cc = t & 31;
        float s = 0.f;
#pragma unroll
        for (int g = 0; g < 16; ++g) s += sacc[(g * 9 + q) * 32 + cc];
        Sout[((size_t)blk * 9 + q) * 32 + cc] = s;
    }
}

// ---------------------------------------------------------------------------
// tail (512 thr): one block per (b, lattice residue (ky0,kx0) == pixel-block).
// Setup: hood combine (p2s candidates) + clst output; stage clstin5 table and
// the 16x16 lattice pixels; 1/den per cell. Final phase runs s2p (t<256,
// thread = target cell, cluster row hoisted to registers) and p2s (t>=256,
// thread = own pixel, b128 sclst reads) CONCURRENTLY.
// ---------------------------------------------------------------------------
__global__ __launch_bounds__(512, 4) void tail_kernel(const float* __restrict__ xn,
                                                      const float* __restrict__ Sin,
                                                      const float* __restrict__ dpin,
                                                      const float* __restrict__ clstin5,
                                                      float* __restrict__ out_clst,
                                                      float* __restrict__ out_p2s,
                                                      float* __restrict__ out_s2p) {
    int blk = blockIdx.x;
    int b = blk >> 8;
    int cell = blk & 255;
    int ky0 = cell >> 4, kx0 = cell & 15;   // lattice residue == pixel-block id
    int t = threadIdx.x;

    __shared__ float bufA[256 * 33];             // clstin5 table (s2p)
    __shared__ float bufB[256 * 33];             // lattice pixel features (s2p)
    __shared__ __align__(16) float sclst[9][32]; // final clst of 3x3 hood (p2s)
    __shared__ float srd[256];                   // 1/den per target cell (s2p)

    // final combine hood (for p2s) + own-cell clst output
    if (t < 288) {
        int q = t >> 5, c = t & 31;
        float v = combine_one(Sin, dpin, b, ky0 + q / 3 - 1, kx0 + q % 3 - 1, c);
        sclst[q][c] = v;
        if (q == 4)
            out_clst[((size_t)b * 32 + c) * 256 + cell] = v;
    }

    // stage clstin5 table
    for (int u = t; u < 8192; u += 512)
        bufA[(u >> 5) * 33 + (u & 31)] = clstin5[(size_t)b * 8192 + u];

    // stage lattice pixels: thread (p = t&255, h = t>>8) -> pixel (16r+ky0, 16s+kx0)
    {
        int p = t & 255, h = t >> 8;
        int r = p >> 4, s = p & 15;
        const float4* f4 = (const float4*)(xn +
            ((size_t)(b * 65536 + (16 * r + ky0) * 256 + 16 * s + kx0)) * 32 + h * 16);
#pragma unroll
        for (int q = 0; q < 4; ++q) {
            float4 v = f4[q];
            bufB[p * 33 + h * 16 + 4*q]     = v.x;
            bufB[p * 33 + h * 16 + 4*q + 1] = v.y;
            bufB[p * 33 + h * 16 + 4*q + 2] = v.z;
            bufB[p * 33 + h * 16 + 4*q + 3] = v.w;
        }
    }

    if (t < 256) {   // 1/den of iteration 5 per target cell t
        int i = t >> 4, j = t & 15;
        float den = 0.f;
#pragma unroll
        for (int u = 0; u < 9; ++u) {
            int oy = u / 3 - 1, ox = u % 3 - 1;
            int ii = i + oy, jj = j + ox;
            if (ii >= 0 && ii < 16 && jj >= 0 && jj < 16)
                den += dpin[((b * 256 + ii * 16 + jj) * 9) + (1 - oy) * 3 + (1 - ox)];
        }
        srd[t] = 1.0f / den;               // den > 0 always (valid cell)
    }
    __syncthreads();

    if (t < 256) {
        // s2p: thread t = target cell (i,j); 9 window positions of this residue
        int i = t >> 4, j = t & 15;
        float clr[32];                     // hoist cluster row into registers
#pragma unroll
        for (int c = 0; c < 32; ++c) clr[c] = bufA[t * 33 + c];
        float rd = srd[t];
#pragma unroll
        for (int a = 0; a < 3; ++a) {
#pragma unroll
            for (int bb = 0; bb < 3; ++bb) {
                int r = i + a - 1, s2 = j + bb - 1;   // lattice coords of pixel
                float val = 0.f;
                if (r >= 0 && r < 16 && s2 >= 0 && s2 < 16) {
                    const float* f = bufB + (r * 16 + s2) * 33;
                    float s = 0.f;
#pragma unroll
                    for (int c = 0; c < 32; ++c) s += f[c] * clr[c];
                    if (s != 0.f) val = SHIFTED_EXP(s) * rd;
                }
                int p = (ky0 + 16 * a) * 48 + kx0 + 16 * bb;
                out_s2p[(size_t)(b * 2304 + p) * 256 + t] = val;
            }
        }
    } else {
        // p2s for own pixel-block (ky0,kx0), pixel = t-256
        int p = t - 256;
        int py = p >> 4, px = p & 15;
        int rem = (ky0 * 16 + py) * 256 + kx0 * 16 + px;
        const float4* f4 = (const float4*)(xn + ((size_t)b * 65536 + rem) * 32);
        float fv[32];
#pragma unroll
        for (int q = 0; q < 8; ++q) {
            float4 v = f4[q];
            fv[4*q] = v.x; fv[4*q+1] = v.y; fv[4*q+2] = v.z; fv[4*q+3] = v.w;
        }
        float l[9];
        float mx = -INFINITY;
#pragma unroll
        for (int q = 0; q < 9; ++q) {
            float s = dot32_lds(fv, sclst[q]);
            l[q] = (s == 0.f) ? -INFINITY : s * TAU_INV;
            mx = fmaxf(mx, l[q]);
        }
        float e[9], sum = 0.f;
#pragma unroll
        for (int q = 0; q < 9; ++q) {
            e[q] = (l[q] == -INFINITY) ? 0.f : expf(l[q] - mx);
            sum += e[q];
        }
        float rs = 1.0f / sum;
#pragma unroll
        for (int q = 0; q < 9; ++q)
            out_p2s[((size_t)b * 9 + q) * 65536 + rem] = e[q] * rs;
    }
}

extern "C" void kernel_launch(void* const* d_in, const int* in_sizes, int n_in,
                              void* d_out, int out_size, void* d_ws, size_t ws_size,
                              hipStream_t stream) {
    const float* x = (const float*)d_in[0];
    float* out = (float*)d_out;

    float* out_clst = out;                       // 2*32*16*16      = 16384
    float* out_p2s  = out + 16384;               // 2*9*256*256     = 1179648
    float* out_s2p  = out + 16384 + 1179648;     // 2*2304*16*16    = 1179648

    float* ws = (float*)d_ws;
    float* xn      = ws;                         // 4,194,304
    float* clst0   = xn + 4194304;               // 16,384
    float* Sa      = clst0 + 16384;              // 147,456
    float* Sb      = Sa + 147456;                // 147,456
    float* dpa     = Sb + 147456;                // 4,608
    float* dpb     = dpa + 4608;                 // 4,608
    float* clstin5 = dpb + 4608;                 // 16,384
    // total ~18.1 MB << ws_size

    prep_init_kernel<<<512, 512, 0, stream>>>(x, xn, clst0);

    // it0 reads clst0 (Sin/dpin unread), writes B; then alternate.
    float* Sin = Sa;  float* dpin = dpa;
    float* Sout = Sb; float* dpout = dpb;
    for (int it = 0; it < 5; ++it) {
        accum9c_kernel<<<512, 512, 0, stream>>>(xn, clst0, Sin, dpin,
                                                Sout, dpout, clstin5, it);
        float* ts = Sin; Sin = Sout; Sout = ts;
        float* td = dpin; dpin = dpout; dpout = td;
    }
    // Sin/dpin now hold S5/dp5
    tail_kernel<<<512, 512, 0, stream>>>(xn, Sin, dpin, clstin5,
                                         out_clst, out_p2s, out_s2p);
}

// Round 12
// 96.965 us; speedup vs baseline: 1.2057x; 1.2057x over previous
//
#include <hip/hip_runtime.h>
#include <math.h>

// Problem constants (b=2, c=32, H=W=256, 256 superpixels, R=1, 5 iters, tau=0.01)
#define TAU_INV 100.0f
// Fixed softmax shift: dots of unit vectors lie in [-1,1]; every cell window's
// max dot is > 0, so with shift 0.5 exponents are in [-150, 50]: e <= 5.2e21
// (no overflow), den > 0 (no all-zero window). Softmax is shift-invariant, so
// ratios match the reference's true-max softmax. Downstream divides by den
// BEFORE squaring (convex combination, ||mean|| <= 1) to avoid f32 overflow.
#define SHIFTED_EXP(s) expf(((s) - 0.5f) * TAU_INV)

// ---------------------------------------------------------------------------
// combine_one: cluster update for target cell (ti,tj) from iteration partials.
// Executed by an aligned 32-lane group; c = lane's channel. Deterministic
// (fixed summation order) so redundant recomputation in different blocks is
// bitwise identical. Returns 0 for out-of-grid targets (matches zero-padding).
// ---------------------------------------------------------------------------
__device__ inline float combine_one(const float* __restrict__ Sin,
                                    const float* __restrict__ dpin,
                                    int b, int ti, int tj, int c) {
    float acc = 0.f, den = 0.f;
    if (ti >= 0 && ti < 16 && tj >= 0 && tj < 16) {
#pragma unroll
        for (int u = 0; u < 9; ++u) {
            int oy = u / 3 - 1, ox = u % 3 - 1;
            int ii = ti + oy, jj = tj + ox;
            if (ii >= 0 && ii < 16 && jj >= 0 && jj < 16) {
                int src = ((b * 256 + ii * 16 + jj) * 9) + (1 - oy) * 3 + (1 - ox);
                acc += Sin[(size_t)src * 32 + c];
                den += dpin[src];
            }
        }
    }
    float mean = (den > 0.f) ? acc / den : 0.f;   // ||mean|| <= 1
    float p = mean * mean;
#pragma unroll
    for (int k = 16; k >= 1; k >>= 1) p += __shfl_xor(p, k);
    return (p > 0.f) ? mean * (1.0f / sqrtf(p)) : 0.f;
}

// ---------------------------------------------------------------------------
// prep_init (512 thr): thread = (pixel p = t&255, channel-half h = t>>8).
//  - per-pixel L2-normalize x -> xn[b][y][x][c] (channel-last)
//  - raw block mean over the 16x16 block, L2-normalized -> clst0[b][cell][c]
// ---------------------------------------------------------------------------
__global__ __launch_bounds__(512, 4) void prep_init_kernel(const float* __restrict__ x,
                                                           float* __restrict__ xn,
                                                           float* __restrict__ clst0) {
    int blk = blockIdx.x;          // b*256 + cell
    int b = blk >> 8;
    int cell = blk & 255;
    int ci = cell >> 4, cj = cell & 15;
    int t = threadIdx.x;
    int p = t & 255, h = t >> 8;
    int py = p >> 4, px = p & 15;
    int rem = (ci * 16 + py) * 256 + cj * 16 + px;

    __shared__ float sraw[256 * 33];   // padded stride 33
    __shared__ float ssh[512];
    __shared__ float red[512];

    const float* xb = x + (size_t)b * (32 * 65536);
    float v[16];
    float ssp = 0.f;
#pragma unroll
    for (int k = 0; k < 16; ++k) {
        int c = h * 16 + k;
        float tv = xb[c * 65536 + rem];
        v[k] = tv;
        ssp += tv * tv;
        sraw[p * 33 + c] = tv;
    }
    ssh[t] = ssp;
    __syncthreads();
    float rn = 1.0f / sqrtf(ssh[p] + ssh[p + 256]);
    {
        float4* outp = (float4*)(xn + ((size_t)b * 65536 + rem) * 32 + h * 16);
#pragma unroll
        for (int q = 0; q < 4; ++q)
            outp[q] = make_float4(v[4*q]*rn, v[4*q+1]*rn, v[4*q+2]*rn, v[4*q+3]*rn);
    }
    // block mean: thread = (c = t&31, pg = t>>5, 16 groups of 16 pixels)
    {
        int c = t & 31, pg = t >> 5;
        float acc = 0.f;
#pragma unroll
        for (int k = 0; k < 16; ++k) acc += sraw[(pg * 16 + k) * 33 + c];
        red[t] = acc;
    }
    __syncthreads();
    if (t < 256) red[t] += red[t + 256];
    __syncthreads();
    if (t < 128) red[t] += red[t + 128];
    __syncthreads();
    if (t < 64) red[t] += red[t + 64];
    __syncthreads();
    if (t < 32) {
        float m = (red[t] + red[t + 32]) * (1.0f / 256.0f);
        float pp = m * m;
#pragma unroll
        for (int k = 16; k >= 1; k >>= 1) pp += __shfl_xor(pp, k);
        clst0[(size_t)blk * 32 + t] = m * (1.0f / sqrtf(pp));
    }
}

// ---------------------------------------------------------------------------
// accum9c (512 thr): one block per (b, pixel-block).
// Pixel loads are issued FIRST so their latency overlaps the head-combine's
// scattered global reads (G7). Head: 9 neighbor clusters from clst0 (it==0)
// or redundant deterministic combine of prev partials (it>=1).
// Dots: thread = (pixel p = t&255, half h = t>>8); h=0 -> q 0..3, h=1 -> 4..8.
// Accumulation: thread = (c = t&31, pg = t>>5, 16 pixels each).
// ---------------------------------------------------------------------------
__global__ __launch_bounds__(512, 4) void accum9c_kernel(const float* __restrict__ xn,
                                                         const float* __restrict__ clst0,
                                                         const float* __restrict__ Sin,
                                                         const float* __restrict__ dpin,
                                                         float* __restrict__ Sout,
                                                         float* __restrict__ dpout,
                                                         float* __restrict__ clstin5,
                                                         int it) {
    int blk = blockIdx.x;           // b*256 + block
    int b = blk >> 8;
    int cell = blk & 255;
    int bi = cell >> 4, bj = cell & 15;
    int t = threadIdx.x;

    __shared__ float sx[256 * 33];      // block's pixel features
    __shared__ float se[9 * 256];
    __shared__ float sacc[16 * 9 * 32];
    __shared__ float sclst[9][32];
    __shared__ float sdw[8][9];

    // ---- issue pixel-feature loads first (overlap with head's global reads) ----
    int p = t & 255, h = t >> 8;
    int y = bi * 16 + (p >> 4), xx = bj * 16 + (p & 15);
    const float4* f4 = (const float4*)(xn + ((size_t)(b * 65536 + y * 256 + xx)) * 32);
    float fv[32];
#pragma unroll
    for (int q = 0; q < 8; ++q) {
        float4 v = f4[q];
        fv[4*q] = v.x; fv[4*q+1] = v.y; fv[4*q+2] = v.z; fv[4*q+3] = v.w;
    }

    // ---- head: 9 neighbor clusters ----
    if (it == 0) {
        if (t < 288) {
            int q = t >> 5, c = t & 31;
            int ii = bi + q / 3 - 1, jj = bj + q % 3 - 1;
            float v = 0.f;
            if (ii >= 0 && ii < 16 && jj >= 0 && jj < 16)
                v = clst0[((size_t)(b * 256 + ii * 16 + jj)) * 32 + c];
            sclst[q][c] = v;
        }
    } else {
        if (t < 288) {
            int q = t >> 5, c = t & 31;
            float v = combine_one(Sin, dpin, b, bi + q / 3 - 1, bj + q % 3 - 1, c);
            sclst[q][c] = v;
            if (it == 4 && q == 4)                   // own cell = iter-5 input clst
                clstin5[(size_t)blk * 32 + c] = v;
        }
    }
    if (h == 0) {
#pragma unroll
        for (int c = 0; c < 32; ++c) sx[p * 33 + c] = fv[c];
    }
    __syncthreads();

    int wid = t >> 6, lane = t & 63;
    if (h == 0) {
#pragma unroll
        for (int q = 0; q < 4; ++q) {
            float s = 0.f;
#pragma unroll
            for (int c = 0; c < 32; ++c) s += fv[c] * sclst[q][c];
            // s==0 <=> OOB target (sclst=0) or exact-zero dot; ref masks both.
            float ev = (s == 0.f) ? 0.f : SHIFTED_EXP(s);
            se[q * 256 + p] = ev;
            float d = ev;
#pragma unroll
            for (int k = 32; k >= 1; k >>= 1) d += __shfl_xor(d, k);
            if (lane == 0) sdw[wid][q] = d;
        }
    } else {
#pragma unroll
        for (int q = 4; q < 9; ++q) {
            float s = 0.f;
#pragma unroll
            for (int c = 0; c < 32; ++c) s += fv[c] * sclst[q][c];
            float ev = (s == 0.f) ? 0.f : SHIFTED_EXP(s);
            se[q * 256 + p] = ev;
            float d = ev;
#pragma unroll
            for (int k = 32; k >= 1; k >>= 1) d += __shfl_xor(d, k);
            if (lane == 0) sdw[wid][q] = d;
        }
    }
    __syncthreads();
    if (t < 9) {
        int w0 = (t < 4) ? 0 : 4;
        dpout[blk * 9 + t] = sdw[w0][t] + sdw[w0+1][t] + sdw[w0+2][t] + sdw[w0+3][t];
    }

    // accumulation: thread = (c = t&31, pg = t>>5), 16 pixels each, 9 targets
    {
        int c = t & 31, pg = t >> 5;
        float acc[9];
#pragma unroll
        for (int q = 0; q < 9; ++q) acc[q] = 0.f;
#pragma unroll
        for (int k = 0; k < 16; ++k) {
            int pp = pg * 16 + k;
            float xv = sx[pp * 33 + c];
#pragma unroll
            for (int q = 0; q < 9; ++q) acc[q] = fmaf(se[q * 256 + pp], xv, acc[q]);
        }
#pragma unroll
        for (int q = 0; q < 9; ++q) sacc[(pg * 9 + q) * 32 + c] = acc[q];
    }
    __syncthreads();
    if (t < 288) {
        int q = t >> 5, cc = t & 31;
        float s = 0.f;
#pragma unroll
        for (int g = 0; g < 16; ++g) s += sacc[(g * 9 + q) * 32 + cc];
        Sout[((size_t)blk * 9 + q) * 32 + cc] = s;
    }
}

// ---------------------------------------------------------------------------
// tail (512 thr): one block per (b, lattice residue (ky0,kx0) == pixel-block).
// Setup: hood combine (p2s candidates) + clst output; stage clstin5 table and
// the 16x16 lattice pixels; 1/den per cell. Final phase runs s2p (t<256,
// thread = target cell) and p2s (t>=256, thread = own pixel) CONCURRENTLY.
// ---------------------------------------------------------------------------
__global__ __launch_bounds__(512, 4) void tail_kernel(const float* __restrict__ xn,
                                                      const float* __restrict__ Sin,
                                                      const float* __restrict__ dpin,
                                                      const float* __restrict__ clstin5,
                                                      float* __restrict__ out_clst,
                                                      float* __restrict__ out_p2s,
                                                      float* __restrict__ out_s2p) {
    int blk = blockIdx.x;
    int b = blk >> 8;
    int cell = blk & 255;
    int ky0 = cell >> 4, kx0 = cell & 15;   // lattice residue == pixel-block id
    int t = threadIdx.x;

    __shared__ float bufA[256 * 33];   // clstin5 table (s2p)
    __shared__ float bufB[256 * 33];   // lattice pixel features (s2p)
    __shared__ float sclst[9][32];     // final clst of 3x3 hood (p2s)
    __shared__ float srd[256];         // 1/den per target cell (s2p)

    // final combine hood (for p2s) + own-cell clst output
    if (t < 288) {
        int q = t >> 5, c = t & 31;
        float v = combine_one(Sin, dpin, b, ky0 + q / 3 - 1, kx0 + q % 3 - 1, c);
        sclst[q][c] = v;
        if (q == 4)
            out_clst[((size_t)b * 32 + c) * 256 + cell] = v;
    }

    // stage clstin5 table
    for (int u = t; u < 8192; u += 512)
        bufA[(u >> 5) * 33 + (u & 31)] = clstin5[(size_t)b * 8192 + u];

    // stage lattice pixels: thread (p = t&255, h = t>>8) -> pixel (16r+ky0, 16s+kx0)
    {
        int p = t & 255, h = t >> 8;
        int r = p >> 4, s = p & 15;
        const float4* f4 = (const float4*)(xn +
            ((size_t)(b * 65536 + (16 * r + ky0) * 256 + 16 * s + kx0)) * 32 + h * 16);
#pragma unroll
        for (int q = 0; q < 4; ++q) {
            float4 v = f4[q];
            bufB[p * 33 + h * 16 + 4*q]     = v.x;
            bufB[p * 33 + h * 16 + 4*q + 1] = v.y;
            bufB[p * 33 + h * 16 + 4*q + 2] = v.z;
            bufB[p * 33 + h * 16 + 4*q + 3] = v.w;
        }
    }

    if (t < 256) {   // 1/den of iteration 5 per target cell t
        int i = t >> 4, j = t & 15;
        float den = 0.f;
#pragma unroll
        for (int u = 0; u < 9; ++u) {
            int oy = u / 3 - 1, ox = u % 3 - 1;
            int ii = i + oy, jj = j + ox;
            if (ii >= 0 && ii < 16 && jj >= 0 && jj < 16)
                den += dpin[((b * 256 + ii * 16 + jj) * 9) + (1 - oy) * 3 + (1 - ox)];
        }
        srd[t] = 1.0f / den;               // den > 0 always (valid cell)
    }
    __syncthreads();

    if (t < 256) {
        // s2p: thread t = target cell (i,j); 9 window positions of this residue
        int i = t >> 4, j = t & 15;
        const float* cl = bufA + t * 33;
        float rd = srd[t];
#pragma unroll
        for (int a = 0; a < 3; ++a) {
#pragma unroll
            for (int bb = 0; bb < 3; ++bb) {
                int r = i + a - 1, s2 = j + bb - 1;   // lattice coords of pixel
                float val = 0.f;
                if (r >= 0 && r < 16 && s2 >= 0 && s2 < 16) {
                    const float* f = bufB + (r * 16 + s2) * 33;
                    float s = 0.f;
#pragma unroll
                    for (int c = 0; c < 32; ++c) s += f[c] * cl[c];
                    if (s != 0.f) val = SHIFTED_EXP(s) * rd;
                }
                int p = (ky0 + 16 * a) * 48 + kx0 + 16 * bb;
                out_s2p[(size_t)(b * 2304 + p) * 256 + t] = val;
            }
        }
    } else {
        // p2s for own pixel-block (ky0,kx0), pixel = t-256
        int p = t - 256;
        int py = p >> 4, px = p & 15;
        int rem = (ky0 * 16 + py) * 256 + kx0 * 16 + px;
        const float4* f4 = (const float4*)(xn + ((size_t)b * 65536 + rem) * 32);
        float fv[32];
#pragma unroll
        for (int q = 0; q < 8; ++q) {
            float4 v = f4[q];
            fv[4*q] = v.x; fv[4*q+1] = v.y; fv[4*q+2] = v.z; fv[4*q+3] = v.w;
        }
        float l[9];
        float mx = -INFINITY;
#pragma unroll
        for (int q = 0; q < 9; ++q) {
            float s = 0.f;
#pragma unroll
            for (int c = 0; c < 32; ++c) s += fv[c] * sclst[q][c];
            l[q] = (s == 0.f) ? -INFINITY : s * TAU_INV;
            mx = fmaxf(mx, l[q]);
        }
        float e[9], sum = 0.f;
#pragma unroll
        for (int q = 0; q < 9; ++q) {
            e[q] = (l[q] == -INFINITY) ? 0.f : expf(l[q] - mx);
            sum += e[q];
        }
        float rs = 1.0f / sum;
#pragma unroll
        for (int q = 0; q < 9; ++q)
            out_p2s[((size_t)b * 9 + q) * 65536 + rem] = e[q] * rs;
    }
}

extern "C" void kernel_launch(void* const* d_in, const int* in_sizes, int n_in,
                              void* d_out, int out_size, void* d_ws, size_t ws_size,
                              hipStream_t stream) {
    const float* x = (const float*)d_in[0];
    float* out = (float*)d_out;

    float* out_clst = out;                       // 2*32*16*16      = 16384
    float* out_p2s  = out + 16384;               // 2*9*256*256     = 1179648
    float* out_s2p  = out + 16384 + 1179648;     // 2*2304*16*16    = 1179648

    float* ws = (float*)d_ws;
    float* xn      = ws;                         // 4,194,304
    float* clst0   = xn + 4194304;               // 16,384
    float* Sa      = clst0 + 16384;              // 147,456
    float* Sb      = Sa + 147456;                // 147,456
    float* dpa     = Sb + 147456;                // 4,608
    float* dpb     = dpa + 4608;                 // 4,608
    float* clstin5 = dpb + 4608;                 // 16,384
    // total ~18.1 MB << ws_size

    prep_init_kernel<<<512, 512, 0, stream>>>(x, xn, clst0);

    // it0 reads clst0 (Sin/dpin unread), writes B; then alternate.
    float* Sin = Sa;  float* dpin = dpa;
    float* Sout = Sb; float* dpout = dpb;
    for (int it = 0; it < 5; ++it) {
        accum9c_kernel<<<512, 512, 0, stream>>>(xn, clst0, Sin, dpin,
                                                Sout, dpout, clstin5, it);
        float* ts = Sin; Sin = Sout; Sout = ts;
        float* td = dpin; dpin = dpout; dpout = td;
    }
    // Sin/dpin now hold S5/dp5
    tail_kernel<<<512, 512, 0, stream>>>(xn, Sin, dpin, clstin5,
                                         out_clst, out_p2s, out_s2p);
}

// Round 13
// 94.853 us; speedup vs baseline: 1.2326x; 1.0223x over previous
//
#include <hip/hip_runtime.h>
#include <math.h>

// Problem constants (b=2, c=32, H=W=256, 256 superpixels, R=1, 5 iters, tau=0.01)
#define TAU_INV 100.0f
// Fixed softmax shift: dots of unit vectors lie in [-1,1]; every cell window's
// max dot is > 0, so with shift 0.5 exponents are in [-150, 50]: e <= 5.2e21
// (no overflow), den > 0 (no all-zero window). Softmax is shift-invariant, so
// ratios match the reference's true-max softmax. Downstream divides by den
// BEFORE squaring (convex combination, ||mean|| <= 1) to avoid f32 overflow.
#define SHIFTED_EXP(s) expf(((s) - 0.5f) * TAU_INV)

// ---------------------------------------------------------------------------
// combine_one: cluster update for target cell (ti,tj) from iteration partials.
// Executed by an aligned 32-lane group; c = lane's channel. Deterministic
// (fixed summation order) so redundant recomputation in different blocks is
// bitwise identical. Returns 0 for out-of-grid targets (matches zero-padding).
// ---------------------------------------------------------------------------
__device__ inline float combine_one(const float* __restrict__ Sin,
                                    const float* __restrict__ dpin,
                                    int b, int ti, int tj, int c) {
    float acc = 0.f, den = 0.f;
    if (ti >= 0 && ti < 16 && tj >= 0 && tj < 16) {
#pragma unroll
        for (int u = 0; u < 9; ++u) {
            int oy = u / 3 - 1, ox = u % 3 - 1;
            int ii = ti + oy, jj = tj + ox;
            if (ii >= 0 && ii < 16 && jj >= 0 && jj < 16) {
                int src = ((b * 256 + ii * 16 + jj) * 9) + (1 - oy) * 3 + (1 - ox);
                acc += Sin[(size_t)src * 32 + c];
                den += dpin[src];
            }
        }
    }
    float mean = (den > 0.f) ? acc / den : 0.f;   // ||mean|| <= 1
    float p = mean * mean;
#pragma unroll
    for (int k = 16; k >= 1; k >>= 1) p += __shfl_xor(p, k);
    return (p > 0.f) ? mean * (1.0f / sqrtf(p)) : 0.f;
}

// ---------------------------------------------------------------------------
// prep_init (512 thr): thread = (pixel p = t&255, channel-half h = t>>8).
//  - per-pixel L2-normalize x -> xn[b][y][x][c] (channel-last)
//  - raw block mean over the 16x16 block, L2-normalized -> clst0[b][cell][c]
// ---------------------------------------------------------------------------
__global__ __launch_bounds__(512, 4) void prep_init_kernel(const float* __restrict__ x,
                                                           float* __restrict__ xn,
                                                           float* __restrict__ clst0) {
    int blk = blockIdx.x;          // b*256 + cell
    int b = blk >> 8;
    int cell = blk & 255;
    int ci = cell >> 4, cj = cell & 15;
    int t = threadIdx.x;
    int p = t & 255, h = t >> 8;
    int py = p >> 4, px = p & 15;
    int rem = (ci * 16 + py) * 256 + cj * 16 + px;

    __shared__ float sraw[256 * 33];   // padded stride 33
    __shared__ float ssh[512];
    __shared__ float red[512];

    const float* xb = x + (size_t)b * (32 * 65536);
    float v[16];
    float ssp = 0.f;
#pragma unroll
    for (int k = 0; k < 16; ++k) {
        int c = h * 16 + k;
        float tv = xb[c * 65536 + rem];
        v[k] = tv;
        ssp += tv * tv;
        sraw[p * 33 + c] = tv;
    }
    ssh[t] = ssp;
    __syncthreads();
    float rn = 1.0f / sqrtf(ssh[p] + ssh[p + 256]);
    {
        float4* outp = (float4*)(xn + ((size_t)b * 65536 + rem) * 32 + h * 16);
#pragma unroll
        for (int q = 0; q < 4; ++q)
            outp[q] = make_float4(v[4*q]*rn, v[4*q+1]*rn, v[4*q+2]*rn, v[4*q+3]*rn);
    }
    // block mean: thread = (c = t&31, pg = t>>5, 16 groups of 16 pixels)
    {
        int c = t & 31, pg = t >> 5;
        float acc = 0.f;
#pragma unroll
        for (int k = 0; k < 16; ++k) acc += sraw[(pg * 16 + k) * 33 + c];
        red[t] = acc;
    }
    __syncthreads();
    if (t < 256) red[t] += red[t + 256];
    __syncthreads();
    if (t < 128) red[t] += red[t + 128];
    __syncthreads();
    if (t < 64) red[t] += red[t + 64];
    __syncthreads();
    if (t < 32) {
        float m = (red[t] + red[t + 32]) * (1.0f / 256.0f);
        float pp = m * m;
#pragma unroll
        for (int k = 16; k >= 1; k >>= 1) pp += __shfl_xor(pp, k);
        clst0[(size_t)blk * 32 + t] = m * (1.0f / sqrtf(pp));
    }
}

// ---------------------------------------------------------------------------
// accum9c (512 thr): one block per (b, pixel-block).
// Head: 9 neighbor clusters from clst0 (it==0) or redundant deterministic
// combine of prev partials (it>=1) -- threads 0..287, q = t>>5.
// Dots: thread = (pixel p = t&255, half h = t>>8); h=0 -> q 0..3, h=1 -> 4..8.
// Accumulation: thread = (c = t&31, pg = t>>5, 16 pixels each).
// ---------------------------------------------------------------------------
__global__ __launch_bounds__(512, 4) void accum9c_kernel(const float* __restrict__ xn,
                                                         const float* __restrict__ clst0,
                                                         const float* __restrict__ Sin,
                                                         const float* __restrict__ dpin,
                                                         float* __restrict__ Sout,
                                                         float* __restrict__ dpout,
                                                         float* __restrict__ clstin5,
                                                         int it) {
    int blk = blockIdx.x;           // b*256 + block
    int b = blk >> 8;
    int cell = blk & 255;
    int bi = cell >> 4, bj = cell & 15;
    int t = threadIdx.x;

    __shared__ float sx[256 * 33];      // block's pixel features
    __shared__ float se[9 * 256];
    __shared__ float sacc[16 * 9 * 32];
    __shared__ float sclst[9][32];
    __shared__ float sdw[8][9];

    if (it == 0) {
        if (t < 288) {
            int q = t >> 5, c = t & 31;
            int ii = bi + q / 3 - 1, jj = bj + q % 3 - 1;
            float v = 0.f;
            if (ii >= 0 && ii < 16 && jj >= 0 && jj < 16)
                v = clst0[((size_t)(b * 256 + ii * 16 + jj)) * 32 + c];
            sclst[q][c] = v;
        }
    } else {
        if (t < 288) {
            int q = t >> 5, c = t & 31;
            float v = combine_one(Sin, dpin, b, bi + q / 3 - 1, bj + q % 3 - 1, c);
            sclst[q][c] = v;
            if (it == 4 && q == 4)                   // own cell = iter-5 input clst
                clstin5[(size_t)blk * 32 + c] = v;
        }
    }
    __syncthreads();

    int p = t & 255, h = t >> 8;
    int y = bi * 16 + (p >> 4), xx = bj * 16 + (p & 15);
    const float4* f4 = (const float4*)(xn + ((size_t)(b * 65536 + y * 256 + xx)) * 32);
    float fv[32];
#pragma unroll
    for (int q = 0; q < 8; ++q) {
        float4 v = f4[q];
        fv[4*q] = v.x; fv[4*q+1] = v.y; fv[4*q+2] = v.z; fv[4*q+3] = v.w;
    }
    if (h == 0) {
#pragma unroll
        for (int c = 0; c < 32; ++c) sx[p * 33 + c] = fv[c];
    }

    int wid = t >> 6, lane = t & 63;
    if (h == 0) {
#pragma unroll
        for (int q = 0; q < 4; ++q) {
            float s = 0.f;
#pragma unroll
            for (int c = 0; c < 32; ++c) s += fv[c] * sclst[q][c];
            // s==0 <=> OOB target (sclst=0) or exact-zero dot; ref masks both.
            float ev = (s == 0.f) ? 0.f : SHIFTED_EXP(s);
            se[q * 256 + p] = ev;
            float d = ev;
#pragma unroll
            for (int k = 32; k >= 1; k >>= 1) d += __shfl_xor(d, k);
            if (lane == 0) sdw[wid][q] = d;
        }
    } else {
#pragma unroll
        for (int q = 4; q < 9; ++q) {
            float s = 0.f;
#pragma unroll
            for (int c = 0; c < 32; ++c) s += fv[c] * sclst[q][c];
            float ev = (s == 0.f) ? 0.f : SHIFTED_EXP(s);
            se[q * 256 + p] = ev;
            float d = ev;
#pragma unroll
            for (int k = 32; k >= 1; k >>= 1) d += __shfl_xor(d, k);
            if (lane == 0) sdw[wid][q] = d;
        }
    }
    __syncthreads();
    if (t < 9) {
        int w0 = (t < 4) ? 0 : 4;
        dpout[blk * 9 + t] = sdw[w0][t] + sdw[w0+1][t] + sdw[w0+2][t] + sdw[w0+3][t];
    }

    // accumulation: thread = (c = t&31, pg = t>>5), 16 pixels each, 9 targets
    {
        int c = t & 31, pg = t >> 5;
        float acc[9];
#pragma unroll
        for (int q = 0; q < 9; ++q) acc[q] = 0.f;
#pragma unroll
        for (int k = 0; k < 16; ++k) {
            int pp = pg * 16 + k;
            float xv = sx[pp * 33 + c];
#pragma unroll
            for (int q = 0; q < 9; ++q) acc[q] = fmaf(se[q * 256 + pp], xv, acc[q]);
        }
#pragma unroll
        for (int q = 0; q < 9; ++q) sacc[(pg * 9 + q) * 32 + c] = acc[q];
    }
    __syncthreads();
    if (t < 288) {
        int q = t >> 5, cc = t & 31;
        float s = 0.f;
#pragma unroll
        for (int g = 0; g < 16; ++g) s += sacc[(g * 9 + q) * 32 + cc];
        Sout[((size_t)blk * 9 + q) * 32 + cc] = s;
    }
}

// ---------------------------------------------------------------------------
// tail (512 thr): one block per (b, lattice residue (ky0,kx0) == pixel-block).
// Setup: hood combine (p2s candidates) + clst output; stage clstin5 table and
// the 16x16 lattice pixels; 1/den per cell. Final phase runs s2p (t<256,
// thread = target cell) and p2s (t>=256, thread = own pixel) CONCURRENTLY.
// ---------------------------------------------------------------------------
__global__ __launch_bounds__(512, 4) void tail_kernel(const float* __restrict__ xn,
                                                      const float* __restrict__ Sin,
                                                      const float* __restrict__ dpin,
                                                      const float* __restrict__ clstin5,
                                                      float* __restrict__ out_clst,
                                                      float* __restrict__ out_p2s,
                                                      float* __restrict__ out_s2p) {
    int blk = blockIdx.x;
    int b = blk >> 8;
    int cell = blk & 255;
    int ky0 = cell >> 4, kx0 = cell & 15;   // lattice residue == pixel-block id
    int t = threadIdx.x;

    __shared__ float bufA[256 * 33];   // clstin5 table (s2p)
    __shared__ float bufB[256 * 33];   // lattice pixel features (s2p)
    __shared__ float sclst[9][32];     // final clst of 3x3 hood (p2s)
    __shared__ float srd[256];         // 1/den per target cell (s2p)

    // final combine hood (for p2s) + own-cell clst output
    if (t < 288) {
        int q = t >> 5, c = t & 31;
        float v = combine_one(Sin, dpin, b, ky0 + q / 3 - 1, kx0 + q % 3 - 1, c);
        sclst[q][c] = v;
        if (q == 4)
            out_clst[((size_t)b * 32 + c) * 256 + cell] = v;
    }

    // stage clstin5 table
    for (int u = t; u < 8192; u += 512)
        bufA[(u >> 5) * 33 + (u & 31)] = clstin5[(size_t)b * 8192 + u];

    // stage lattice pixels: thread (p = t&255, h = t>>8) -> pixel (16r+ky0, 16s+kx0)
    {
        int p = t & 255, h = t >> 8;
        int r = p >> 4, s = p & 15;
        const float4* f4 = (const float4*)(xn +
            ((size_t)(b * 65536 + (16 * r + ky0) * 256 + 16 * s + kx0)) * 32 + h * 16);
#pragma unroll
        for (int q = 0; q < 4; ++q) {
            float4 v = f4[q];
            bufB[p * 33 + h * 16 + 4*q]     = v.x;
            bufB[p * 33 + h * 16 + 4*q + 1] = v.y;
            bufB[p * 33 + h * 16 + 4*q + 2] = v.z;
            bufB[p * 33 + h * 16 + 4*q + 3] = v.w;
        }
    }

    if (t < 256) {   // 1/den of iteration 5 per target cell t
        int i = t >> 4, j = t & 15;
        float den = 0.f;
#pragma unroll
        for (int u = 0; u < 9; ++u) {
            int oy = u / 3 - 1, ox = u % 3 - 1;
            int ii = i + oy, jj = j + ox;
            if (ii >= 0 && ii < 16 && jj >= 0 && jj < 16)
                den += dpin[((b * 256 + ii * 16 + jj) * 9) + (1 - oy) * 3 + (1 - ox)];
        }
        srd[t] = 1.0f / den;               // den > 0 always (valid cell)
    }
    __syncthreads();

    if (t < 256) {
        // s2p: thread t = target cell (i,j); 9 window positions of this residue
        int i = t >> 4, j = t & 15;
        const float* cl = bufA + t * 33;
        float rd = srd[t];
#pragma unroll
        for (int a = 0; a < 3; ++a) {
#pragma unroll
            for (int bb = 0; bb < 3; ++bb) {
                int r = i + a - 1, s2 = j + bb - 1;   // lattice coords of pixel
                float val = 0.f;
                if (r >= 0 && r < 16 && s2 >= 0 && s2 < 16) {
                    const float* f = bufB + (r * 16 + s2) * 33;
                    float s = 0.f;
#pragma unroll
                    for (int c = 0; c < 32; ++c) s += f[c] * cl[c];
                    if (s != 0.f) val = SHIFTED_EXP(s) * rd;
                }
                int p = (ky0 + 16 * a) * 48 + kx0 + 16 * bb;
                out_s2p[(size_t)(b * 2304 + p) * 256 + t] = val;
            }
        }
    } else {
        // p2s for own pixel-block (ky0,kx0), pixel = t-256
        int p = t - 256;
        int py = p >> 4, px = p & 15;
        int rem = (ky0 * 16 + py) * 256 + kx0 * 16 + px;
        const float4* f4 = (const float4*)(xn + ((size_t)b * 65536 + rem) * 32);
        float fv[32];
#pragma unroll
        for (int q = 0; q < 8; ++q) {
            float4 v = f4[q];
            fv[4*q] = v.x; fv[4*q+1] = v.y; fv[4*q+2] = v.z; fv[4*q+3] = v.w;
        }
        float l[9];
        float mx = -INFINITY;
#pragma unroll
        for (int q = 0; q < 9; ++q) {
            float s = 0.f;
#pragma unroll
            for (int c = 0; c < 32; ++c) s += fv[c] * sclst[q][c];
            l[q] = (s == 0.f) ? -INFINITY : s * TAU_INV;
            mx = fmaxf(mx, l[q]);
        }
        float e[9], sum = 0.f;
#pragma unroll
        for (int q = 0; q < 9; ++q) {
            e[q] = (l[q] == -INFINITY) ? 0.f : expf(l[q] - mx);
            sum += e[q];
        }
        float rs = 1.0f / sum;
#pragma unroll
        for (int q = 0; q < 9; ++q)
            out_p2s[((size_t)b * 9 + q) * 65536 + rem] = e[q] * rs;
    }
}

extern "C" void kernel_launch(void* const* d_in, const int* in_sizes, int n_in,
                              void* d_out, int out_size, void* d_ws, size_t ws_size,
                              hipStream_t stream) {
    const float* x = (const float*)d_in[0];
    float* out = (float*)d_out;

    float* out_clst = out;                       // 2*32*16*16      = 16384
    float* out_p2s  = out + 16384;               // 2*9*256*256     = 1179648
    float* out_s2p  = out + 16384 + 1179648;     // 2*2304*16*16    = 1179648

    float* ws = (float*)d_ws;
    float* xn      = ws;                         // 4,194,304
    float* clst0   = xn + 4194304;               // 16,384
    float* Sa      = clst0 + 16384;              // 147,456
    float* Sb      = Sa + 147456;                // 147,456
    float* dpa     = Sb + 147456;                // 4,608
    float* dpb     = dpa + 4608;                 // 4,608
    float* clstin5 = dpb + 4608;                 // 16,384
    // total ~18.1 MB << ws_size

    prep_init_kernel<<<512, 512, 0, stream>>>(x, xn, clst0);

    // it0 reads clst0 (Sin/dpin unread), writes B; then alternate.
    float* Sin = Sa;  float* dpin = dpa;
    float* Sout = Sb; float* dpout = dpb;
    for (int it = 0; it < 5; ++it) {
        accum9c_kernel<<<512, 512, 0, stream>>>(xn, clst0, Sin, dpin,
                                                Sout, dpout, clstin5, it);
        float* ts = Sin; Sin = Sout; Sout = ts;
        float* td = dpin; dpin = dpout; dpout = td;
    }
    // Sin/dpin now hold S5/dp5
    tail_kernel<<<512, 512, 0, stream>>>(xn, Sin, dpin, clstin5,
                                         out_clst, out_p2s, out_s2p);
}